// Round 4
// baseline (330.497 us; speedup 1.0000x reference)
//
#include <hip/hip_runtime.h>
#include <stdint.h>

typedef unsigned long long ull;

#define NA 8400
#define NB 32
#define KTOP 300
#define NC 80
#define CH 33            // 256*33 = 8448 >= 8400

// ws layout:
//   [b*WS_STRIDE .. +33600)  : per-batch region. First used as keys (uint32[8400],
//                              written by score, read by select), then overwritten by
//                              select with keep-words + boxes.
#define WS_STRIDE 33600
#define OFF_KEEP  0        // ull[5]      keep-init bit words
#define OFF_BOX   64       // float4[300] selected boxes (x1,y1,x2,y2)
//   global side arrays (written by score, read by select):
#define XYWH_OFF  1075200  // float4[268800] (x,y,w,h)       = 32*33600
#define META_OFF  5376000  // float4[268800] (obj,conf,cls,0)

// out layout: boxes_yxyx @0 ; in_zone @38400 ; scores @48000 ; classes @57600 ;
//             centers_yx @67200 ; keep @86400 ; total 96000 floats
#define O1 38400
#define O2 48000
#define O3 57600
#define O4 67200
#define O5 86400

// ---------------- A: per-anchor score key + packed detail arrays ----------------
__global__ __launch_bounds__(128) void score_kernel(const float* __restrict__ pred,
                                                    uint32_t* __restrict__ keys,
                                                    float4* __restrict__ xywh4,
                                                    float4* __restrict__ meta4) {
    __shared__ float sP[128 * 85];
    const int blk = blockIdx.x;                       // 2100 blocks * 128 anchors
    const int t = threadIdx.x;
    const float4* g4 = (const float4*)(pred + (size_t)blk * 128 * 85);
    float4* l4 = (float4*)sP;
    for (int i = t; i < (128 * 85 / 4); i += 128) l4[i] = g4[i];
    __syncthreads();
    const float* p = sP + t * 85;                     // stride 85 dwords: odd -> 2-way bank alias (free)
    float x = p[0], y = p[1], w = p[2], h = p[3], obj = p[4];
    // 4 interleaved first-max chains (strict > keeps lowest index within chain)
    float b0 = p[5], b1 = p[6], b2 = p[7], b3 = p[8];
    int i0 = 0, i1 = 1, i2 = 2, i3 = 3;
    #pragma unroll
    for (int c = 4; c < NC; c += 4) {
        float v0 = p[5 + c], v1 = p[6 + c], v2 = p[7 + c], v3 = p[8 + c];
        if (v0 > b0) { b0 = v0; i0 = c; }
        if (v1 > b1) { b1 = v1; i1 = c + 1; }
        if (v2 > b2) { b2 = v2; i2 = c + 2; }
        if (v3 > b3) { b3 = v3; i3 = c + 3; }
    }
    float best = fmaxf(fmaxf(b0, b1), fmaxf(b2, b3));
    int bi = 0x7FFFFFFF;                              // overall first max = min index among equal chain winners
    if (b3 == best) bi = i3;
    if (b2 == best && i2 < bi) bi = i2;
    if (b1 == best && i1 < bi) bi = i1;
    if (b0 == best && i0 < bi) bi = i0;
    float sc = obj * best;
    uint32_t u = (sc >= 0.2f) ? (__float_as_uint(sc) | 0x80000000u) : 0x007FFFFFu;
    const size_t gi = (size_t)blk * 128 + t;
    keys[gi] = u;
    xywh4[gi] = make_float4(x, y, w, h);
    meta4[gi] = make_float4(obj, best, (float)bi, 0.0f);
}

// ---------------- B: per-batch exact sorted top-300 + detail outputs ----------------
__global__ __launch_bounds__(256) void select_kernel(const uint32_t* __restrict__ keys,
                                                     const float4* __restrict__ xywh4,
                                                     const float4* __restrict__ meta4,
                                                     uint8_t* ws,
                                                     float* __restrict__ out) {
    #pragma clang fp contract(off)
    __shared__ uint32_t sKeys[8448];
    __shared__ ull sSel[KTOP];
    __shared__ ull sSorted[KTOP];
    __shared__ uint32_t sHist[256];
    __shared__ uint32_t sWs[8];       // [0..3] wave sums, [4..7] exclusive wave offsets
    __shared__ uint32_t sBc[2];
    __shared__ int sCnt;

    const int b = blockIdx.x;
    const int t = threadIdx.x;
    const unsigned lane = t & 63;
    const int wv = t >> 6;

    for (int e = t; e < NA; e += 256) sKeys[e] = keys[(size_t)b * NA + e];
    for (int e = NA + t; e < 8448; e += 256) sKeys[e] = 0u;
    if (t == 0) sCnt = 0;
    __syncthreads();

    // ---- radix select: exact 300th-largest key ----
    uint32_t prefix = 0, r = KTOP;
    for (int round = 0; round < 4; ++round) {
        const int shift = 24 - 8 * round;
        sHist[t] = 0u;
        __syncthreads();
        const uint32_t pmask = (round == 0) ? 0u : (0xFFFFFFFFu << (shift + 8));
        const uint32_t pval = prefix & pmask;
        // wave ballot-aggregated histogram: one atomic per distinct bin per step
        for (int s = 0; s < CH; ++s) {
            int e = t * CH + s;
            bool act = (e < NA);
            uint32_t k = act ? sKeys[e] : 0u;
            act = act && ((k & pmask) == pval);
            uint32_t bin = (k >> shift) & 0xFFu;
            ull todo = __ballot(act);
            while (todo) {
                int leader = __builtin_ctzll(todo);
                uint32_t lbin = __shfl((int)bin, leader);
                ull eq = __ballot(act && (bin == lbin));
                if (lane == (unsigned)leader)
                    atomicAdd(&sHist[lbin], (uint32_t)__popcll(eq));
                todo &= ~eq;
            }
        }
        __syncthreads();
        // inclusive prefix scan over 256 bins: wave shfl scan + cross-wave combine
        uint32_t h = sHist[t];
        uint32_t val = h;
        #pragma unroll
        for (int d = 1; d < 64; d <<= 1) {
            uint32_t v = __shfl_up(val, d);
            if (lane >= (unsigned)d) val += v;
        }
        if (lane == 63) sWs[wv] = val;
        __syncthreads();
        if (t == 0) {
            uint32_t a = sWs[0], b2 = sWs[1], c = sWs[2];
            sWs[4] = 0; sWs[5] = a; sWs[6] = a + b2; sWs[7] = a + b2 + c;
        }
        __syncthreads();
        uint32_t P = val + sWs[4 + wv];          // count of keys with byte <= t (in match set)
        uint32_t Total = sWs[7] + sWs[3];
        uint32_t above = Total - P;              // count with byte > t
        if (above < r && above + h >= r) {       // unique crossing bin
            sBc[0] = prefix | ((uint32_t)t << shift);
            sBc[1] = r - above;
        }
        __syncthreads();
        prefix = sBc[0]; r = sBc[1];
        __syncthreads();
    }
    const uint32_t kth = prefix;
    const uint32_t rem = r;
    const uint32_t cntgt = KTOP - rem;

    // ---- compact the top-300 set into sSel (unordered) ----
    {
        uint32_t eqc = 0;
        for (int s = 0; s < CH; ++s) {
            int e = t * CH + s;
            if (e < NA) {
                uint32_t k = sKeys[e];
                if (k > kth) {
                    int p = atomicAdd(&sCnt, 1);
                    sSel[p] = ((ull)k << 32) | (ull)(0xFFFFFFFFu - (uint32_t)e);
                } else if (k == kth) eqc++;
            }
        }
        uint32_t val = eqc;
        #pragma unroll
        for (int d = 1; d < 64; d <<= 1) {
            uint32_t v = __shfl_up(val, d);
            if (lane >= (unsigned)d) val += v;
        }
        if (lane == 63) sWs[wv] = val;
        __syncthreads();
        if (t == 0) {
            uint32_t a = sWs[0], b2 = sWs[1], c = sWs[2];
            sWs[4] = 0; sWs[5] = a; sWs[6] = a + b2; sWs[7] = a + b2 + c;
        }
        __syncthreads();
        uint32_t off0 = val - eqc + sWs[4 + wv];     // exclusive prefix of eq-counts
        for (int s = 0; s < CH; ++s) {
            int e = t * CH + s;
            if (e < NA) {
                uint32_t k = sKeys[e];
                if (k == kth) {
                    if (off0 < rem)
                        sSel[cntgt + off0] = ((ull)k << 32) | (ull)(0xFFFFFFFFu - (uint32_t)e);
                    off0++;
                }
            }
        }
        __syncthreads();
    }

    // ---- rank sort: entries unique -> ranks are a permutation ----
    ull my0 = sSel[t];
    ull my1 = (t < KTOP - 256) ? sSel[256 + t] : 0ull;
    int r0 = 0, r1 = 0;
    for (int j = 0; j < KTOP; ++j) {
        ull v = sSel[j];                 // broadcast read
        r0 += (v > my0) ? 1 : 0;
        r1 += (v > my1) ? 1 : 0;
    }
    sSorted[r0] = my0;
    if (t < KTOP - 256) sSorted[r1] = my1;
    __syncthreads();

    // ---- keep-init ballots ----
    ull* keepW = (ull*)(ws + (size_t)b * WS_STRIDE + OFF_KEEP);
    {
        bool f = ((uint32_t)(sSorted[t] >> 32)) > 0x007FFFFFu;
        ull m = __ballot(f);
        if (lane == 0) keepW[wv] = m;
        if (t < 64) {
            bool f2 = (t < KTOP - 256) && (((uint32_t)(sSorted[256 + t] >> 32)) > 0x007FFFFFu);
            ull m2 = __ballot(f2);
            if (t == 0) keepW[4] = m2;
        }
    }

    // ---- gather packed details, write boxes to ws + keep-independent outputs ----
    float4* wsBox = (float4*)(ws + (size_t)b * WS_STRIDE + OFF_BOX);
    const size_t bo = (size_t)b * KTOP;
    for (int i = t; i < KTOP; i += 256) {
        ull s = sSorted[i];
        uint32_t a = 0xFFFFFFFFu - (uint32_t)(s & 0xFFFFFFFFull);
        size_t g = (size_t)b * NA + a;
        float4 xw = xywh4[g];
        float4 mt = meta4[g];
        float hw = xw.z * 0.5f, hh = xw.w * 0.5f;
        float x1 = xw.x - hw, y1 = xw.y - hh, x2 = xw.x + hw, y2 = xw.y + hh;
        wsBox[i] = make_float4(x1, y1, x2, y2);
        ((float4*)out)[bo + i] = make_float4(y1, x1, y2, x2);          // boxes_yxyx
        ((float2*)(out + O4))[bo + i] = make_float2((y1 + y2) * 0.5f,  // centers_yx
                                                    (x1 + x2) * 0.5f);
        out[O2 + bo + i] = fmaxf(mt.x, mt.y);                          // scores
        out[O3 + bo + i] = mt.z;                                       // classes
    }
}

// ---------------- C: IoU masks (LDS) + greedy NMS + keep/in_zone outputs ----------------
__global__ __launch_bounds__(256) void finish_kernel(const float* __restrict__ zone,
                                                     const uint8_t* __restrict__ ws,
                                                     float* __restrict__ out) {
    #pragma clang fp contract(off)
    __shared__ float4 sBox[KTOP];
    __shared__ ull sMask[5 * KTOP];      // role-major: sMask[role*300 + i]
    __shared__ ull sKeepOut[5];
    __shared__ float sZone[16];
    const int b = blockIdx.x;
    const int t = threadIdx.x;
    const float4* wsBox = (const float4*)(ws + (size_t)b * WS_STRIDE + OFF_BOX);
    const ull* keepW = (const ull*)(ws + (size_t)b * WS_STRIDE + OFF_KEEP);

    if (t < 16) sZone[t] = zone[t];
    for (int i = t; i < KTOP; i += 256) sBox[i] = wsBox[i];
    __syncthreads();

    // masks: bit j of sMask[role*300+i] set iff j>i && iou(i,j)>0.45, j in [role*64, role*64+64)
    for (int item = t; item < 5 * KTOP; item += 256) {
        int role = item / KTOP;          // lanes share role, consecutive i -> uniform j-loop
        int i = item - role * KTOP;
        float4 B = sBox[i];
        float x1 = B.x, y1 = B.y, x2 = B.z, y2 = B.w;
        float ai = fmaxf(x2 - x1, 0.0f) * fmaxf(y2 - y1, 0.0f);
        ull bits = 0ull;
        int j0 = role * 64;
        int jmax = j0 + 64; if (jmax > KTOP) jmax = KTOP;
        int jbeg = (j0 > i + 1) ? j0 : (i + 1);
        for (int j = jbeg; j < jmax; ++j) {
            float4 C = sBox[j];          // broadcast read
            float aj = fmaxf(C.z - C.x, 0.0f) * fmaxf(C.w - C.y, 0.0f);
            float iw = fminf(x2, C.z) - fmaxf(x1, C.x); iw = fmaxf(iw, 0.0f);
            float ih = fminf(y2, C.w) - fmaxf(y1, C.y); ih = fmaxf(ih, 0.0f);
            float inter = iw * ih;
            float den = ai + aj;         // mirror reference op order exactly
            den = den - inter;
            den = den + 1e-9f;
            float iou = inter / den;
            if (iou > 0.45f) bits |= (1ull << (j - j0));
        }
        sMask[item] = bits;
    }
    __syncthreads();

    // greedy NMS on wave 0: masks in registers, ctz skip between accepted boxes
    if (t < 64) {
        ull rm[5][5];                    // rm[w][ww]: suppression row of box i=w*64+lane, word ww
        #pragma unroll
        for (int w = 0; w < 5; ++w) {
            int i = w * 64 + t;
            #pragma unroll
            for (int ww = 0; ww < 5; ++ww)
                rm[w][ww] = (i < KTOP) ? sMask[ww * KTOP + i] : 0ull;
        }
        ull kw[5];
        #pragma unroll
        for (int w = 0; w < 5; ++w) kw[w] = keepW[w];    // replicated in every lane
        #pragma unroll
        for (int w = 0; w < 5; ++w) {
            ull cur = kw[w];
            while (cur) {
                int ib = __builtin_ctzll(cur);           // accepted box i = w*64+ib
                ull m0 = __shfl(rm[w][0], ib);
                ull m1 = __shfl(rm[w][1], ib);
                ull m2 = __shfl(rm[w][2], ib);
                ull m3 = __shfl(rm[w][3], ib);
                ull m4 = __shfl(rm[w][4], ib);
                kw[0] &= ~m0; kw[1] &= ~m1; kw[2] &= ~m2; kw[3] &= ~m3; kw[4] &= ~m4;
                ull done = (ib == 63) ? 0ull : (~0ull << (ib + 1));
                cur = kw[w] & done;
            }
        }
        if (t == 0) {
            #pragma unroll
            for (int w = 0; w < 5; ++w) sKeepOut[w] = kw[w];
        }
    }
    __syncthreads();

    const size_t bo = (size_t)b * KTOP;
    for (int i = t; i < KTOP; i += 256) {
        int kp = (int)((sKeepOut[i >> 6] >> (i & 63)) & 1ull);
        float4 B = sBox[i];
        float cy = (B.y + B.w) * 0.5f;   // same inputs & ops as select's centers
        float cx = (B.x + B.z) * 0.5f;
        int cnt = 0;
        #pragma unroll
        for (int e = 0; e < 8; ++e) {
            float xi = sZone[2 * e], yi = sZone[2 * e + 1];
            int ep = (e + 7) & 7;        // zr = roll(zone, 1)
            float xj = sZone[2 * ep], yj = sZone[2 * ep + 1];
            bool gyi = yi > cy, gyj = yj > cy;
            if (gyi != gyj) {
                float gx = (xj - xi) * (cy - yi) / (yj - yi) + xi;
                if (gx > cx) cnt++;
            }
        }
        int inz = (((cnt & 1) != 0) && kp) ? 1 : 0;
        out[O1 + bo + i] = (float)inz;
        out[O5 + bo + i] = (float)kp;
    }
}

extern "C" void kernel_launch(void* const* d_in, const int* in_sizes, int n_in,
                              void* d_out, int out_size, void* d_ws, size_t ws_size,
                              hipStream_t stream) {
    const float* pred = (const float*)d_in[0];   // (32,8400,85) fp32
    const float* zone = (const float*)d_in[1];   // (8,2) fp32
    float* out = (float*)d_out;                  // 96000 fp32
    uint8_t* ws = (uint8_t*)d_ws;
    uint32_t* keys = (uint32_t*)ws;              // per-batch 33600-B regions
    float4* xywh4 = (float4*)(ws + XYWH_OFF);
    float4* meta4 = (float4*)(ws + META_OFF);

    score_kernel<<<(NB * NA) / 128, 128, 0, stream>>>(pred, keys, xywh4, meta4);
    select_kernel<<<NB, 256, 0, stream>>>(keys, xywh4, meta4, ws, out);
    finish_kernel<<<NB, 256, 0, stream>>>(zone, ws, out);
}

// Round 5
// 230.554 us; speedup vs baseline: 1.4335x; 1.4335x over previous
//
#include <hip/hip_runtime.h>
#include <stdint.h>

typedef unsigned long long ull;

#define NA 8400
#define NB 32
#define KTOP 300
#define NC 80
#define CH 33            // 256*33 = 8448 >= 8400

// ws layout:
//   [b*WS_STRIDE .. +33600)  : per-batch region. First used as keys (uint32[8400],
//                              written by score, read by select), then overwritten by
//                              select with keep-words + boxes.
#define WS_STRIDE 33600
#define OFF_KEEP  0        // ull[5]      keep-init bit words
#define OFF_BOX   64       // float4[300] selected boxes (x1,y1,x2,y2)
//   global side arrays (written by score, read by select):
#define XYWH_OFF  1075200  // float4[268800] (x,y,w,h)       = 32*33600
#define META_OFF  5376000  // float4[268800] (obj,conf,cls,0)

// out layout: boxes_yxyx @0 ; in_zone @38400 ; scores @48000 ; classes @57600 ;
//             centers_yx @67200 ; keep @86400 ; total 96000 floats
#define O1 38400
#define O2 48000
#define O3 57600
#define O4 67200
#define O5 86400

// ---------------- A: per-anchor score key + packed detail arrays ----------------
__global__ __launch_bounds__(128) void score_kernel(const float* __restrict__ pred,
                                                    uint32_t* __restrict__ keys,
                                                    float4* __restrict__ xywh4,
                                                    float4* __restrict__ meta4) {
    __shared__ float sP[128 * 85];
    const int blk = blockIdx.x;                       // 2100 blocks * 128 anchors
    const int t = threadIdx.x;
    const float4* g4 = (const float4*)(pred + (size_t)blk * 128 * 85);
    float4* l4 = (float4*)sP;
    for (int i = t; i < (128 * 85 / 4); i += 128) l4[i] = g4[i];
    __syncthreads();
    const float* p = sP + t * 85;                     // stride 85 dwords: odd -> 2-way bank alias (free)
    float x = p[0], y = p[1], w = p[2], h = p[3], obj = p[4];
    // 4 interleaved first-max chains (strict > keeps lowest index within chain)
    float b0 = p[5], b1 = p[6], b2 = p[7], b3 = p[8];
    int i0 = 0, i1 = 1, i2 = 2, i3 = 3;
    #pragma unroll
    for (int c = 4; c < NC; c += 4) {
        float v0 = p[5 + c], v1 = p[6 + c], v2 = p[7 + c], v3 = p[8 + c];
        if (v0 > b0) { b0 = v0; i0 = c; }
        if (v1 > b1) { b1 = v1; i1 = c + 1; }
        if (v2 > b2) { b2 = v2; i2 = c + 2; }
        if (v3 > b3) { b3 = v3; i3 = c + 3; }
    }
    float best = fmaxf(fmaxf(b0, b1), fmaxf(b2, b3));
    int bi = 0x7FFFFFFF;                              // overall first max = min index among equal chain winners
    if (b3 == best) bi = i3;
    if (b2 == best && i2 < bi) bi = i2;
    if (b1 == best && i1 < bi) bi = i1;
    if (b0 == best && i0 < bi) bi = i0;
    float sc = obj * best;
    uint32_t u = (sc >= 0.2f) ? (__float_as_uint(sc) | 0x80000000u) : 0x007FFFFFu;
    const size_t gi = (size_t)blk * 128 + t;
    keys[gi] = u;
    xywh4[gi] = make_float4(x, y, w, h);
    meta4[gi] = make_float4(obj, best, (float)bi, 0.0f);
}

// ---------------- B: per-batch exact sorted top-300 + detail outputs ----------------
__global__ __launch_bounds__(256) void select_kernel(const uint32_t* __restrict__ keys,
                                                     const float4* __restrict__ xywh4,
                                                     const float4* __restrict__ meta4,
                                                     uint8_t* ws,
                                                     float* __restrict__ out) {
    #pragma clang fp contract(off)
    __shared__ uint32_t sKeys[8448];
    __shared__ ull sSel[KTOP];
    __shared__ ull sSorted[KTOP];
    __shared__ uint32_t sH8[8 * 256];  // half-wave sub-histograms
    __shared__ uint32_t sWs[8];        // [0..3] wave sums, [4..7] exclusive wave offsets
    __shared__ uint32_t sBc[2];
    __shared__ int sCnt;

    const int b = blockIdx.x;
    const int t = threadIdx.x;
    const unsigned lane = t & 63;
    const int wv = t >> 6;
    const int sh = (t >> 5) << 8;      // half-wave sub-hist base

    for (int e = t; e < NA; e += 256) sKeys[e] = keys[(size_t)b * NA + e];
    for (int e = NA + t; e < 8448; e += 256) sKeys[e] = 0u;
    if (t == 0) sCnt = 0;
    __syncthreads();

    // ---- radix select: exact 300th-largest key ----
    const int beg = t * CH;
    const int end = (beg + CH < NA) ? beg + CH : NA;
    const int nk = (end > beg) ? (end - beg) : 0;
    ull cand = (nk >= 64) ? ~0ull : ((1ull << nk) - 1);   // 33-bit candidate mask
    uint32_t prefix = 0, r = KTOP;
    for (int round = 0; round < 4; ++round) {
        const int shift = 24 - 8 * round;
        for (int idx = t; idx < 2048; idx += 256) sH8[idx] = 0u;
        __syncthreads();
        const uint32_t pmask = (round == 0) ? 0u : (0xFFFFFFFFu << (shift + 8));
        const uint32_t pval = prefix & pmask;
        // visit only surviving candidates; prune those that fell off the prefix
        ull m = cand;
        while (m) {
            int s = __builtin_ctzll(m); m &= m - 1;
            uint32_t k = sKeys[beg + s];
            if ((k & pmask) == pval)
                atomicAdd(&sH8[sh + ((k >> shift) & 0xFFu)], 1u);
            else
                cand &= ~(1ull << s);
        }
        __syncthreads();
        uint32_t h = sH8[t]        + sH8[256 + t]  + sH8[512 + t]  + sH8[768 + t] +
                     sH8[1024 + t] + sH8[1280 + t] + sH8[1536 + t] + sH8[1792 + t];
        // inclusive prefix scan over 256 bins: wave shfl scan + cross-wave combine
        uint32_t val = h;
        #pragma unroll
        for (int d = 1; d < 64; d <<= 1) {
            uint32_t v = __shfl_up(val, d);
            if (lane >= (unsigned)d) val += v;
        }
        if (lane == 63) sWs[wv] = val;
        __syncthreads();
        if (t == 0) {
            uint32_t a = sWs[0], b2 = sWs[1], c = sWs[2];
            sWs[4] = 0; sWs[5] = a; sWs[6] = a + b2; sWs[7] = a + b2 + c;
        }
        __syncthreads();
        uint32_t P = val + sWs[4 + wv];          // count of match-set keys with byte <= t
        uint32_t Total = sWs[7] + sWs[3];
        uint32_t above = Total - P;              // count with byte > t
        if (above < r && above + h >= r) {       // unique crossing bin
            sBc[0] = prefix | ((uint32_t)t << shift);
            sBc[1] = r - above;
        }
        __syncthreads();
        prefix = sBc[0]; r = sBc[1];
        __syncthreads();
    }
    const uint32_t kth = prefix;
    const uint32_t rem = r;
    const uint32_t cntgt = KTOP - rem;

    // ---- compact the top-300 set into sSel (unordered) ----
    {
        uint32_t eqc = 0;
        for (int s = 0; s < CH; ++s) {
            int e = t * CH + s;
            if (e < NA) {
                uint32_t k = sKeys[e];
                if (k > kth) {
                    int p = atomicAdd(&sCnt, 1);
                    sSel[p] = ((ull)k << 32) | (ull)(0xFFFFFFFFu - (uint32_t)e);
                } else if (k == kth) eqc++;
            }
        }
        uint32_t val = eqc;
        #pragma unroll
        for (int d = 1; d < 64; d <<= 1) {
            uint32_t v = __shfl_up(val, d);
            if (lane >= (unsigned)d) val += v;
        }
        if (lane == 63) sWs[wv] = val;
        __syncthreads();
        if (t == 0) {
            uint32_t a = sWs[0], b2 = sWs[1], c = sWs[2];
            sWs[4] = 0; sWs[5] = a; sWs[6] = a + b2; sWs[7] = a + b2 + c;
        }
        __syncthreads();
        uint32_t off0 = val - eqc + sWs[4 + wv];     // exclusive prefix of eq-counts
        for (int s = 0; s < CH; ++s) {
            int e = t * CH + s;
            if (e < NA) {
                uint32_t k = sKeys[e];
                if (k == kth) {
                    if (off0 < rem)
                        sSel[cntgt + off0] = ((ull)k << 32) | (ull)(0xFFFFFFFFu - (uint32_t)e);
                    off0++;
                }
            }
        }
        __syncthreads();
    }

    // ---- rank sort: entries unique -> ranks are a permutation ----
    ull my0 = sSel[t];
    ull my1 = (t < KTOP - 256) ? sSel[256 + t] : 0ull;
    int r0 = 0, r1 = 0;
    for (int j = 0; j < KTOP; ++j) {
        ull v = sSel[j];                 // broadcast read
        r0 += (v > my0) ? 1 : 0;
        r1 += (v > my1) ? 1 : 0;
    }
    sSorted[r0] = my0;
    if (t < KTOP - 256) sSorted[r1] = my1;
    __syncthreads();

    // ---- keep-init ballots ----
    ull* keepW = (ull*)(ws + (size_t)b * WS_STRIDE + OFF_KEEP);
    {
        bool f = ((uint32_t)(sSorted[t] >> 32)) > 0x007FFFFFu;
        ull m = __ballot(f);
        if (lane == 0) keepW[wv] = m;
        if (t < 64) {
            bool f2 = (t < KTOP - 256) && (((uint32_t)(sSorted[256 + t] >> 32)) > 0x007FFFFFu);
            ull m2 = __ballot(f2);
            if (t == 0) keepW[4] = m2;
        }
    }

    // ---- gather packed details, write boxes to ws + keep-independent outputs ----
    float4* wsBox = (float4*)(ws + (size_t)b * WS_STRIDE + OFF_BOX);
    const size_t bo = (size_t)b * KTOP;
    for (int i = t; i < KTOP; i += 256) {
        ull s = sSorted[i];
        uint32_t a = 0xFFFFFFFFu - (uint32_t)(s & 0xFFFFFFFFull);
        size_t g = (size_t)b * NA + a;
        float4 xw = xywh4[g];
        float4 mt = meta4[g];
        float hw = xw.z * 0.5f, hh = xw.w * 0.5f;
        float x1 = xw.x - hw, y1 = xw.y - hh, x2 = xw.x + hw, y2 = xw.y + hh;
        wsBox[i] = make_float4(x1, y1, x2, y2);
        ((float4*)out)[bo + i] = make_float4(y1, x1, y2, x2);          // boxes_yxyx
        ((float2*)(out + O4))[bo + i] = make_float2((y1 + y2) * 0.5f,  // centers_yx
                                                    (x1 + x2) * 0.5f);
        out[O2 + bo + i] = fmaxf(mt.x, mt.y);                          // scores
        out[O3 + bo + i] = mt.z;                                       // classes
    }
}

// ---------------- C: IoU masks (LDS) + greedy NMS + keep/in_zone outputs ----------------
__global__ __launch_bounds__(256) void finish_kernel(const float* __restrict__ zone,
                                                     const uint8_t* __restrict__ ws,
                                                     float* __restrict__ out) {
    #pragma clang fp contract(off)
    __shared__ float4 sBox[KTOP];
    __shared__ ull sMask[5 * KTOP];      // role-major: sMask[role*300 + i]
    __shared__ ull sKeepOut[5];
    __shared__ float sZone[16];
    const int b = blockIdx.x;
    const int t = threadIdx.x;
    const float4* wsBox = (const float4*)(ws + (size_t)b * WS_STRIDE + OFF_BOX);
    const ull* keepW = (const ull*)(ws + (size_t)b * WS_STRIDE + OFF_KEEP);

    if (t < 16) sZone[t] = zone[t];
    for (int i = t; i < KTOP; i += 256) sBox[i] = wsBox[i];
    __syncthreads();

    // masks: bit j of sMask[role*300+i] set iff j>i && iou(i,j)>0.45, j in [role*64, role*64+64)
    for (int item = t; item < 5 * KTOP; item += 256) {
        int role = item / KTOP;          // lanes share role, consecutive i -> uniform j-loop
        int i = item - role * KTOP;
        float4 B = sBox[i];
        float x1 = B.x, y1 = B.y, x2 = B.z, y2 = B.w;
        float ai = fmaxf(x2 - x1, 0.0f) * fmaxf(y2 - y1, 0.0f);
        ull bits = 0ull;
        int j0 = role * 64;
        int jmax = j0 + 64; if (jmax > KTOP) jmax = KTOP;
        int jbeg = (j0 > i + 1) ? j0 : (i + 1);
        for (int j = jbeg; j < jmax; ++j) {
            float4 C = sBox[j];          // broadcast read
            float aj = fmaxf(C.z - C.x, 0.0f) * fmaxf(C.w - C.y, 0.0f);
            float iw = fminf(x2, C.z) - fmaxf(x1, C.x); iw = fmaxf(iw, 0.0f);
            float ih = fminf(y2, C.w) - fmaxf(y1, C.y); ih = fmaxf(ih, 0.0f);
            float inter = iw * ih;
            float den = ai + aj;         // mirror reference op order exactly
            den = den - inter;
            den = den + 1e-9f;
            float iou = inter / den;
            if (iou > 0.45f) bits |= (1ull << (j - j0));
        }
        sMask[item] = bits;
    }
    __syncthreads();

    // greedy NMS on wave 0: masks in registers, ctz skip between accepted boxes
    if (t < 64) {
        ull rm[5][5];                    // rm[w][ww]: suppression row of box i=w*64+lane, word ww
        #pragma unroll
        for (int w = 0; w < 5; ++w) {
            int i = w * 64 + t;
            #pragma unroll
            for (int ww = 0; ww < 5; ++ww)
                rm[w][ww] = (i < KTOP) ? sMask[ww * KTOP + i] : 0ull;
        }
        ull kw[5];
        #pragma unroll
        for (int w = 0; w < 5; ++w) kw[w] = keepW[w];    // replicated in every lane
        #pragma unroll
        for (int w = 0; w < 5; ++w) {
            ull cur = kw[w];
            while (cur) {
                int ib = __builtin_ctzll(cur);           // accepted box i = w*64+ib
                ull m0 = __shfl(rm[w][0], ib);
                ull m1 = __shfl(rm[w][1], ib);
                ull m2 = __shfl(rm[w][2], ib);
                ull m3 = __shfl(rm[w][3], ib);
                ull m4 = __shfl(rm[w][4], ib);
                kw[0] &= ~m0; kw[1] &= ~m1; kw[2] &= ~m2; kw[3] &= ~m3; kw[4] &= ~m4;
                ull done = (ib == 63) ? 0ull : (~0ull << (ib + 1));
                cur = kw[w] & done;
            }
        }
        if (t == 0) {
            #pragma unroll
            for (int w = 0; w < 5; ++w) sKeepOut[w] = kw[w];
        }
    }
    __syncthreads();

    const size_t bo = (size_t)b * KTOP;
    for (int i = t; i < KTOP; i += 256) {
        int kp = (int)((sKeepOut[i >> 6] >> (i & 63)) & 1ull);
        float4 B = sBox[i];
        float cy = (B.y + B.w) * 0.5f;   // same inputs & ops as select's centers
        float cx = (B.x + B.z) * 0.5f;
        int cnt = 0;
        #pragma unroll
        for (int e = 0; e < 8; ++e) {
            float xi = sZone[2 * e], yi = sZone[2 * e + 1];
            int ep = (e + 7) & 7;        // zr = roll(zone, 1)
            float xj = sZone[2 * ep], yj = sZone[2 * ep + 1];
            bool gyi = yi > cy, gyj = yj > cy;
            if (gyi != gyj) {
                float gx = (xj - xi) * (cy - yi) / (yj - yi) + xi;
                if (gx > cx) cnt++;
            }
        }
        int inz = (((cnt & 1) != 0) && kp) ? 1 : 0;
        out[O1 + bo + i] = (float)inz;
        out[O5 + bo + i] = (float)kp;
    }
}

extern "C" void kernel_launch(void* const* d_in, const int* in_sizes, int n_in,
                              void* d_out, int out_size, void* d_ws, size_t ws_size,
                              hipStream_t stream) {
    const float* pred = (const float*)d_in[0];   // (32,8400,85) fp32
    const float* zone = (const float*)d_in[1];   // (8,2) fp32
    float* out = (float*)d_out;                  // 96000 fp32
    uint8_t* ws = (uint8_t*)d_ws;
    uint32_t* keys = (uint32_t*)ws;              // per-batch 33600-B regions
    float4* xywh4 = (float4*)(ws + XYWH_OFF);
    float4* meta4 = (float4*)(ws + META_OFF);

    score_kernel<<<(NB * NA) / 128, 128, 0, stream>>>(pred, keys, xywh4, meta4);
    select_kernel<<<NB, 256, 0, stream>>>(keys, xywh4, meta4, ws, out);
    finish_kernel<<<NB, 256, 0, stream>>>(zone, ws, out);
}

// Round 6
// 230.496 us; speedup vs baseline: 1.4339x; 1.0003x over previous
//
#include <hip/hip_runtime.h>
#include <stdint.h>

typedef unsigned long long ull;

#define NA 8400
#define NB 32
#define KTOP 300
#define NC 80
#define CH 33            // 256*33 = 8448 >= 8400
#define NBLK 66          // score blocks per batch (66*128 = 8448 >= 8400)

// ws layout:
//   [b*WS_STRIDE .. +33600) : per-batch keys (uint32[8400]) written by score, read by
//                             select, then overwritten by select with keep-words + boxes.
#define WS_STRIDE 33600
#define OFF_KEEP  0        // ull[5]      keep-init bit words
#define OFF_BOX   64       // float4[300] selected boxes (x1,y1,x2,y2)
#define XYWH_OFF  1075200  // float4[268800] (x,y,w,h)
#define META_OFF  5376000  // float4[268800] (obj,conf,cls,0)
#define HIST_OFF  9676800  // uint32[32][66][256] per-block byte-0 histograms

// out layout: boxes_yxyx @0 ; in_zone @38400 ; scores @48000 ; classes @57600 ;
//             centers_yx @67200 ; keep @86400 ; total 96000 floats
#define O1 38400
#define O2 48000
#define O3 57600
#define O4 67200
#define O5 86400

// ---------------- A: score key + packed details + per-block byte-0 histogram ----------------
__global__ __launch_bounds__(128) void score_kernel(const float* __restrict__ pred,
                                                    uint32_t* __restrict__ keys,
                                                    float4* __restrict__ xywh4,
                                                    float4* __restrict__ meta4,
                                                    uint32_t* __restrict__ gHist) {
    __shared__ float sP[128 * 85];
    __shared__ uint32_t sH[4 * 257];   // padded sub-hists: hot bins hit distinct banks
    const int batch = blockIdx.x / NBLK;
    const int blk = blockIdx.x - batch * NBLK;
    const int t = threadIdx.x;
    const int local0 = blk * 128;
    const int nval = (NA - local0 < 128) ? (NA - local0) : 128;   // 8400%128=80 tail

    for (int i = t; i < 4 * 257; i += 128) sH[i] = 0u;
    const float4* g4 = (const float4*)(pred + ((size_t)batch * NA + local0) * 85);
    float4* l4 = (float4*)sP;
    const int n4 = nval * 85 / 4;      // 85*nval divisible by 4 (nval = 128 or 80)
    for (int i = t; i < n4; i += 128) l4[i] = g4[i];
    __syncthreads();

    uint32_t u = 0;
    if (t < nval) {
        const float* p = sP + t * 85;
        float x = p[0], y = p[1], w = p[2], h = p[3], obj = p[4];
        // 4 interleaved first-max chains (strict > keeps lowest index within chain)
        float b0 = p[5], b1 = p[6], b2 = p[7], b3 = p[8];
        int i0 = 0, i1 = 1, i2 = 2, i3 = 3;
        #pragma unroll
        for (int c = 4; c < NC; c += 4) {
            float v0 = p[5 + c], v1 = p[6 + c], v2 = p[7 + c], v3 = p[8 + c];
            if (v0 > b0) { b0 = v0; i0 = c; }
            if (v1 > b1) { b1 = v1; i1 = c + 1; }
            if (v2 > b2) { b2 = v2; i2 = c + 2; }
            if (v3 > b3) { b3 = v3; i3 = c + 3; }
        }
        float best = fmaxf(fmaxf(b0, b1), fmaxf(b2, b3));
        int bi = 0x7FFFFFFF;           // overall first max = min index among equal chain winners
        if (b3 == best) bi = i3;
        if (b2 == best && i2 < bi) bi = i2;
        if (b1 == best && i1 < bi) bi = i1;
        if (b0 == best && i0 < bi) bi = i0;
        float sc = obj * best;
        u = (sc >= 0.2f) ? (__float_as_uint(sc) | 0x80000000u) : 0x007FFFFFu;
        const size_t gi = (size_t)batch * NA + local0 + t;
        keys[gi] = u;
        xywh4[gi] = make_float4(x, y, w, h);
        meta4[gi] = make_float4(obj, best, (float)bi, 0.0f);
        atomicAdd(&sH[(t >> 5) * 257 + (u >> 24)], 1u);
    }
    __syncthreads();
    uint32_t* gh = gHist + ((size_t)batch * NBLK + blk) * 256;
    for (int bin = t; bin < 256; bin += 128)
        gh[bin] = sH[bin] + sH[257 + bin] + sH[514 + bin] + sH[771 + bin];
}

// ---------------- B: per-batch exact sorted top-300 + detail outputs ----------------
__global__ __launch_bounds__(256) void select_kernel(const uint32_t* __restrict__ keys,
                                                     const float4* __restrict__ xywh4,
                                                     const float4* __restrict__ meta4,
                                                     const uint32_t* __restrict__ gHist,
                                                     uint8_t* ws,
                                                     float* __restrict__ out) {
    #pragma clang fp contract(off)
    __shared__ uint32_t sKeys[8448];
    __shared__ ull sSel[KTOP];
    __shared__ ull sSorted[KTOP];
    __shared__ uint32_t sH4[4 * 257]; // padded per-wave sub-hists (rounds 1-3)
    __shared__ uint32_t sWs[8];       // [0..3] wave sums, [4..7] exclusive wave offsets
    __shared__ uint32_t sBc[2];
    __shared__ int sCnt;

    const int b = blockIdx.x;
    const int t = threadIdx.x;
    const unsigned lane = t & 63;
    const int wv = t >> 6;
    const int sh = wv * 257;

    for (int e = t; e < NA; e += 256) sKeys[e] = keys[(size_t)b * NA + e];
    for (int e = NA + t; e < 8448; e += 256) sKeys[e] = 0u;
    if (t == 0) sCnt = 0;
    __syncthreads();

    // ---- radix select: exact 300th-largest key; round 0 uses precomputed histogram ----
    uint32_t prefix = 0, r = KTOP;
    for (int round = 0; round < 4; ++round) {
        const int shift = 24 - 8 * round;
        uint32_t h;
        if (round == 0) {
            h = 0;
            const uint32_t* gh = gHist + (size_t)b * NBLK * 256;
            for (int j = 0; j < NBLK; ++j) h += gh[j * 256 + t];   // coalesced over t
        } else {
            for (int idx = t; idx < 4 * 257; idx += 256) sH4[idx] = 0u;
            __syncthreads();
            const uint32_t pmask = 0xFFFFFFFFu << (shift + 8);
            const uint32_t pval = prefix & pmask;
            for (int s = 0; s < CH; ++s) {
                int e = t * CH + s;
                if (e < NA) {
                    uint32_t k = sKeys[e];
                    if ((k & pmask) == pval)
                        atomicAdd(&sH4[sh + ((k >> shift) & 0xFFu)], 1u);
                }
            }
            __syncthreads();
            h = sH4[t] + sH4[257 + t] + sH4[514 + t] + sH4[771 + t];
        }
        // inclusive prefix scan over 256 bins: wave shfl scan + cross-wave combine
        uint32_t val = h;
        #pragma unroll
        for (int d = 1; d < 64; d <<= 1) {
            uint32_t v = __shfl_up(val, d);
            if (lane >= (unsigned)d) val += v;
        }
        if (lane == 63) sWs[wv] = val;
        __syncthreads();
        if (t == 0) {
            uint32_t a = sWs[0], b2 = sWs[1], c = sWs[2];
            sWs[4] = 0; sWs[5] = a; sWs[6] = a + b2; sWs[7] = a + b2 + c;
        }
        __syncthreads();
        uint32_t P = val + sWs[4 + wv];          // match-set keys with byte <= t
        uint32_t Total = sWs[7] + sWs[3];
        uint32_t above = Total - P;              // match-set keys with byte > t
        if (above < r && above + h >= r) {       // unique crossing bin
            sBc[0] = prefix | ((uint32_t)t << shift);
            sBc[1] = r - above;
        }
        __syncthreads();
        prefix = sBc[0]; r = sBc[1];
        __syncthreads();
    }
    const uint32_t kth = prefix;
    const uint32_t rem = r;
    const uint32_t cntgt = KTOP - rem;

    // ---- compact the top-300 set into sSel (unordered) ----
    {
        uint32_t eqc = 0;
        for (int s = 0; s < CH; ++s) {
            int e = t * CH + s;
            if (e < NA) {
                uint32_t k = sKeys[e];
                if (k > kth) {
                    int p = atomicAdd(&sCnt, 1);
                    sSel[p] = ((ull)k << 32) | (ull)(0xFFFFFFFFu - (uint32_t)e);
                } else if (k == kth) eqc++;
            }
        }
        uint32_t val = eqc;
        #pragma unroll
        for (int d = 1; d < 64; d <<= 1) {
            uint32_t v = __shfl_up(val, d);
            if (lane >= (unsigned)d) val += v;
        }
        if (lane == 63) sWs[wv] = val;
        __syncthreads();
        if (t == 0) {
            uint32_t a = sWs[0], b2 = sWs[1], c = sWs[2];
            sWs[4] = 0; sWs[5] = a; sWs[6] = a + b2; sWs[7] = a + b2 + c;
        }
        __syncthreads();
        uint32_t off0 = val - eqc + sWs[4 + wv];     // exclusive prefix of eq-counts
        for (int s = 0; s < CH; ++s) {
            int e = t * CH + s;
            if (e < NA) {
                uint32_t k = sKeys[e];
                if (k == kth) {
                    if (off0 < rem)
                        sSel[cntgt + off0] = ((ull)k << 32) | (ull)(0xFFFFFFFFu - (uint32_t)e);
                    off0++;
                }
            }
        }
        __syncthreads();
    }

    // ---- rank sort: entries unique -> ranks are a permutation ----
    ull my0 = sSel[t];
    ull my1 = (t < KTOP - 256) ? sSel[256 + t] : 0ull;
    int r0 = 0, r1 = 0;
    for (int j = 0; j < KTOP; ++j) {
        ull v = sSel[j];                 // broadcast read
        r0 += (v > my0) ? 1 : 0;
        r1 += (v > my1) ? 1 : 0;
    }
    sSorted[r0] = my0;
    if (t < KTOP - 256) sSorted[r1] = my1;
    __syncthreads();

    // ---- keep-init ballots ----
    ull* keepW = (ull*)(ws + (size_t)b * WS_STRIDE + OFF_KEEP);
    {
        bool f = ((uint32_t)(sSorted[t] >> 32)) > 0x007FFFFFu;
        ull m = __ballot(f);
        if (lane == 0) keepW[wv] = m;
        if (t < 64) {
            bool f2 = (t < KTOP - 256) && (((uint32_t)(sSorted[256 + t] >> 32)) > 0x007FFFFFu);
            ull m2 = __ballot(f2);
            if (t == 0) keepW[4] = m2;
        }
    }

    // ---- gather packed details, write boxes to ws + keep-independent outputs ----
    float4* wsBox = (float4*)(ws + (size_t)b * WS_STRIDE + OFF_BOX);
    const size_t bo = (size_t)b * KTOP;
    for (int i = t; i < KTOP; i += 256) {
        ull s = sSorted[i];
        uint32_t a = 0xFFFFFFFFu - (uint32_t)(s & 0xFFFFFFFFull);
        size_t g = (size_t)b * NA + a;
        float4 xw = xywh4[g];
        float4 mt = meta4[g];
        float hw = xw.z * 0.5f, hh = xw.w * 0.5f;
        float x1 = xw.x - hw, y1 = xw.y - hh, x2 = xw.x + hw, y2 = xw.y + hh;
        wsBox[i] = make_float4(x1, y1, x2, y2);
        ((float4*)out)[bo + i] = make_float4(y1, x1, y2, x2);          // boxes_yxyx
        ((float2*)(out + O4))[bo + i] = make_float2((y1 + y2) * 0.5f,  // centers_yx
                                                    (x1 + x2) * 0.5f);
        out[O2 + bo + i] = fmaxf(mt.x, mt.y);                          // scores
        out[O3 + bo + i] = mt.z;                                       // classes
    }
}

// ---------------- C: IoU masks (LDS) + greedy NMS + keep/in_zone outputs ----------------
__global__ __launch_bounds__(256) void finish_kernel(const float* __restrict__ zone,
                                                     const uint8_t* __restrict__ ws,
                                                     float* __restrict__ out) {
    #pragma clang fp contract(off)
    __shared__ float4 sBox[KTOP];
    __shared__ ull sMask[5 * KTOP];      // role-major: sMask[role*300 + i]
    __shared__ ull sKeepOut[5];
    __shared__ float sZone[16];
    const int b = blockIdx.x;
    const int t = threadIdx.x;
    const float4* wsBox = (const float4*)(ws + (size_t)b * WS_STRIDE + OFF_BOX);
    const ull* keepW = (const ull*)(ws + (size_t)b * WS_STRIDE + OFF_KEEP);

    if (t < 16) sZone[t] = zone[t];
    for (int i = t; i < KTOP; i += 256) sBox[i] = wsBox[i];
    __syncthreads();

    // masks: bit j of sMask[role*300+i] set iff j>i && iou(i,j)>0.45, j in [role*64, role*64+64)
    for (int item = t; item < 5 * KTOP; item += 256) {
        int role = item / KTOP;          // lanes share role, consecutive i -> uniform j-loop
        int i = item - role * KTOP;
        float4 B = sBox[i];
        float x1 = B.x, y1 = B.y, x2 = B.z, y2 = B.w;
        float ai = fmaxf(x2 - x1, 0.0f) * fmaxf(y2 - y1, 0.0f);
        ull bits = 0ull;
        int j0 = role * 64;
        int jmax = j0 + 64; if (jmax > KTOP) jmax = KTOP;
        int jbeg = (j0 > i + 1) ? j0 : (i + 1);
        for (int j = jbeg; j < jmax; ++j) {
            float4 C = sBox[j];          // broadcast read
            float aj = fmaxf(C.z - C.x, 0.0f) * fmaxf(C.w - C.y, 0.0f);
            float iw = fminf(x2, C.z) - fmaxf(x1, C.x); iw = fmaxf(iw, 0.0f);
            float ih = fminf(y2, C.w) - fmaxf(y1, C.y); ih = fmaxf(ih, 0.0f);
            float inter = iw * ih;
            float den = ai + aj;         // mirror reference op order exactly
            den = den - inter;
            den = den + 1e-9f;
            float iou = inter / den;
            if (iou > 0.45f) bits |= (1ull << (j - j0));
        }
        sMask[item] = bits;
    }
    __syncthreads();

    // greedy NMS on wave 0: masks in registers, ctz skip between accepted boxes
    if (t < 64) {
        ull rm[5][5];                    // rm[w][ww]: suppression row of box i=w*64+lane, word ww
        #pragma unroll
        for (int w = 0; w < 5; ++w) {
            int i = w * 64 + t;
            #pragma unroll
            for (int ww = 0; ww < 5; ++ww)
                rm[w][ww] = (i < KTOP) ? sMask[ww * KTOP + i] : 0ull;
        }
        ull kw[5];
        #pragma unroll
        for (int w = 0; w < 5; ++w) kw[w] = keepW[w];    // replicated in every lane
        #pragma unroll
        for (int w = 0; w < 5; ++w) {
            ull cur = kw[w];
            while (cur) {
                int ib = __builtin_ctzll(cur);           // accepted box i = w*64+ib
                ull m0 = __shfl(rm[w][0], ib);
                ull m1 = __shfl(rm[w][1], ib);
                ull m2 = __shfl(rm[w][2], ib);
                ull m3 = __shfl(rm[w][3], ib);
                ull m4 = __shfl(rm[w][4], ib);
                kw[0] &= ~m0; kw[1] &= ~m1; kw[2] &= ~m2; kw[3] &= ~m3; kw[4] &= ~m4;
                ull done = (ib == 63) ? 0ull : (~0ull << (ib + 1));
                cur = kw[w] & done;
            }
        }
        if (t == 0) {
            #pragma unroll
            for (int w = 0; w < 5; ++w) sKeepOut[w] = kw[w];
        }
    }
    __syncthreads();

    const size_t bo = (size_t)b * KTOP;
    for (int i = t; i < KTOP; i += 256) {
        int kp = (int)((sKeepOut[i >> 6] >> (i & 63)) & 1ull);
        float4 B = sBox[i];
        float cy = (B.y + B.w) * 0.5f;   // same inputs & ops as select's centers
        float cx = (B.x + B.z) * 0.5f;
        int cnt = 0;
        #pragma unroll
        for (int e = 0; e < 8; ++e) {
            float xi = sZone[2 * e], yi = sZone[2 * e + 1];
            int ep = (e + 7) & 7;        // zr = roll(zone, 1)
            float xj = sZone[2 * ep], yj = sZone[2 * ep + 1];
            bool gyi = yi > cy, gyj = yj > cy;
            if (gyi != gyj) {
                float gx = (xj - xi) * (cy - yi) / (yj - yi) + xi;
                if (gx > cx) cnt++;
            }
        }
        int inz = (((cnt & 1) != 0) && kp) ? 1 : 0;
        out[O1 + bo + i] = (float)inz;
        out[O5 + bo + i] = (float)kp;
    }
}

extern "C" void kernel_launch(void* const* d_in, const int* in_sizes, int n_in,
                              void* d_out, int out_size, void* d_ws, size_t ws_size,
                              hipStream_t stream) {
    const float* pred = (const float*)d_in[0];   // (32,8400,85) fp32
    const float* zone = (const float*)d_in[1];   // (8,2) fp32
    float* out = (float*)d_out;                  // 96000 fp32
    uint8_t* ws = (uint8_t*)d_ws;
    uint32_t* keys = (uint32_t*)ws;              // per-batch 33600-B regions
    float4* xywh4 = (float4*)(ws + XYWH_OFF);
    float4* meta4 = (float4*)(ws + META_OFF);
    uint32_t* gHist = (uint32_t*)(ws + HIST_OFF);

    score_kernel<<<NB * NBLK, 128, 0, stream>>>(pred, keys, xywh4, meta4, gHist);
    select_kernel<<<NB, 256, 0, stream>>>(keys, xywh4, meta4, gHist, ws, out);
    finish_kernel<<<NB, 256, 0, stream>>>(zone, ws, out);
}

// Round 7
// 216.931 us; speedup vs baseline: 1.5235x; 1.0625x over previous
//
#include <hip/hip_runtime.h>
#include <stdint.h>

typedef unsigned long long ull;

#define NA 8400
#define NB 32
#define KTOP 300
#define NC 80
#define CH 33            // 256*33 = 8448 >= 8400
#define NBLK 66          // score blocks per batch (66*128 = 8448 >= 8400)

// ws layout: keys uint32[32][8400] @0 ; gHist uint32[32][66][256] @HIST_OFF
#define HIST_OFF 1075200

// out layout: boxes_yxyx @0 ; in_zone @38400 ; scores @48000 ; classes @57600 ;
//             centers_yx @67200 ; keep @86400 ; total 96000 floats
#define O1 38400
#define O2 48000
#define O3 57600
#define O4 67200
#define O5 86400

// async global->LDS, 16B per lane; lds dest = wave-uniform base + lane*16
__device__ __forceinline__ void g2l16(const void* g, void* l) {
    __builtin_amdgcn_global_load_lds(
        (const __attribute__((address_space(1))) void*)g,
        (__attribute__((address_space(3))) void*)l, 16, 0, 0);
}

// ---------------- A: score key + per-block byte-0 histogram ----------------
__global__ __launch_bounds__(128) void score_kernel(const float* __restrict__ pred,
                                                    uint32_t* __restrict__ keys,
                                                    uint32_t* __restrict__ gHist) {
    __shared__ float sP[128 * 85];
    __shared__ uint32_t sH[4 * 257];   // padded half-wave sub-hists (hot bins -> distinct banks)
    const int batch = blockIdx.x / NBLK;
    const int blk = blockIdx.x - batch * NBLK;
    const int t = threadIdx.x;
    const int lane = t & 63;
    const int wv = t >> 6;
    const int local0 = blk * 128;
    const int nval = (NA - local0 < 128) ? (NA - local0) : 128;   // tail block: 80

    for (int i = t; i < 4 * 257; i += 128) sH[i] = 0u;

    // async staging: contiguous lane order, wave-uniform LDS base
    const float4* g4 = (const float4*)(pred + ((size_t)batch * NA + local0) * 85);
    float4* l4 = (float4*)sP;
    const int n4 = nval * 85 / 4;      // 2720 or 1700 (both divisible by 4? 1700*4=6800=80*85 ok)
    for (int base = wv * 64; base < n4; base += 128) {
        int idx = base + lane;
        if (idx < n4) g2l16(g4 + idx, l4 + base);
    }
    __syncthreads();                   // drains vmcnt + lgkmcnt

    if (t < nval) {
        const float* p = sP + t * 85;
        float obj = p[4];
        // 4 interleaved max chains (max only; argmax recomputed later for winners)
        float b0 = p[5], b1 = p[6], b2 = p[7], b3 = p[8];
        #pragma unroll
        for (int c = 4; c < NC; c += 4) {
            b0 = fmaxf(b0, p[5 + c]);
            b1 = fmaxf(b1, p[6 + c]);
            b2 = fmaxf(b2, p[7 + c]);
            b3 = fmaxf(b3, p[8 + c]);
        }
        float best = fmaxf(fmaxf(b0, b1), fmaxf(b2, b3));
        float sc = obj * best;
        uint32_t u = (sc >= 0.2f) ? (__float_as_uint(sc) | 0x80000000u) : 0x007FFFFFu;
        keys[(size_t)batch * NA + local0 + t] = u;
        atomicAdd(&sH[(t >> 5) * 257 + (u >> 24)], 1u);
    }
    __syncthreads();
    uint32_t* gh = gHist + ((size_t)batch * NBLK + blk) * 256;
    for (int bin = t; bin < 256; bin += 128)
        gh[bin] = sH[bin] + sH[257 + bin] + sH[514 + bin] + sH[771 + bin];
}

// ---------------- B: fused top-300 select + gather + NMS + all outputs ----------------
__global__ __launch_bounds__(256) void topk_nms_kernel(const float* __restrict__ pred,
                                                       const float* __restrict__ zone,
                                                       const uint32_t* __restrict__ keys,
                                                       const uint32_t* __restrict__ gHist,
                                                       float* __restrict__ out) {
    #pragma clang fp contract(off)
    __shared__ uint32_t sKeys[8448];   // 33792 B
    __shared__ ull sSel[KTOP];
    __shared__ ull sSorted[KTOP];      // 4800 B
    __shared__ uint32_t sH4[4 * 257];  // 4112 B padded per-wave sub-hists (rounds 1-3)
    __shared__ float4 sBox[KTOP];      // 4800 B
    __shared__ ull sMask[5 * KTOP];    // 12000 B role-major: sMask[role*300 + i]
    __shared__ ull sKeepW[5];
    __shared__ float sZone[16];
    __shared__ uint32_t sWs[8];        // [0..3] wave sums, [4..7] exclusive wave offsets
    __shared__ uint32_t sBc[2];
    __shared__ int sCnt;

    const int b = blockIdx.x;
    const int t = threadIdx.x;
    const unsigned lane = t & 63;
    const int wv = t >> 6;
    const int sh = wv * 257;

    // async-load keys into LDS (2100 float4s), pad tail, load zone
    {
        const float4* k4 = (const float4*)(keys + (size_t)b * NA);
        float4* sk4 = (float4*)sKeys;
        for (int base = wv * 64; base < 2100; base += 256) {
            int idx = base + lane;
            if (idx < 2100) g2l16(k4 + idx, sk4 + base);
        }
    }
    if (t < 48) sKeys[NA + t] = 0u;
    if (t < 16) sZone[t] = zone[t];
    if (t == 0) sCnt = 0;
    __syncthreads();

    // ---- radix select: exact 300th-largest key; round 0 from precomputed histogram ----
    uint32_t prefix = 0, r = KTOP;
    for (int round = 0; round < 4; ++round) {
        const int shift = 24 - 8 * round;
        uint32_t h;
        if (round == 0) {
            h = 0;
            const uint32_t* gh = gHist + (size_t)b * NBLK * 256;
            for (int j = 0; j < NBLK; ++j) h += gh[j * 256 + t];   // coalesced over t
        } else {
            for (int idx = t; idx < 4 * 257; idx += 256) sH4[idx] = 0u;
            __syncthreads();
            const uint32_t pmask = 0xFFFFFFFFu << (shift + 8);
            const uint32_t pval = prefix & pmask;
            for (int s = 0; s < CH; ++s) {
                int e = t * CH + s;
                if (e < NA) {
                    uint32_t k = sKeys[e];
                    if ((k & pmask) == pval)
                        atomicAdd(&sH4[sh + ((k >> shift) & 0xFFu)], 1u);
                }
            }
            __syncthreads();
            h = sH4[t] + sH4[257 + t] + sH4[514 + t] + sH4[771 + t];
        }
        // inclusive prefix scan over 256 bins: wave shfl scan + cross-wave combine
        uint32_t val = h;
        #pragma unroll
        for (int d = 1; d < 64; d <<= 1) {
            uint32_t v = __shfl_up(val, d);
            if (lane >= (unsigned)d) val += v;
        }
        if (lane == 63) sWs[wv] = val;
        __syncthreads();
        if (t == 0) {
            uint32_t a = sWs[0], b2 = sWs[1], c = sWs[2];
            sWs[4] = 0; sWs[5] = a; sWs[6] = a + b2; sWs[7] = a + b2 + c;
        }
        __syncthreads();
        uint32_t P = val + sWs[4 + wv];          // match-set keys with byte <= t
        uint32_t Total = sWs[7] + sWs[3];
        uint32_t above = Total - P;              // match-set keys with byte > t
        if (above < r && above + h >= r) {       // unique crossing bin
            sBc[0] = prefix | ((uint32_t)t << shift);
            sBc[1] = r - above;
        }
        __syncthreads();
        prefix = sBc[0]; r = sBc[1];
        __syncthreads();
    }
    const uint32_t kth = prefix;
    const uint32_t rem = r;
    const uint32_t cntgt = KTOP - rem;

    // ---- compact the top-300 set into sSel (unordered) ----
    {
        uint32_t eqc = 0;
        for (int s = 0; s < CH; ++s) {
            int e = t * CH + s;
            if (e < NA) {
                uint32_t k = sKeys[e];
                if (k > kth) {
                    int p = atomicAdd(&sCnt, 1);
                    sSel[p] = ((ull)k << 32) | (ull)(0xFFFFFFFFu - (uint32_t)e);
                } else if (k == kth) eqc++;
            }
        }
        uint32_t val = eqc;
        #pragma unroll
        for (int d = 1; d < 64; d <<= 1) {
            uint32_t v = __shfl_up(val, d);
            if (lane >= (unsigned)d) val += v;
        }
        if (lane == 63) sWs[wv] = val;
        __syncthreads();
        if (t == 0) {
            uint32_t a = sWs[0], b2 = sWs[1], c = sWs[2];
            sWs[4] = 0; sWs[5] = a; sWs[6] = a + b2; sWs[7] = a + b2 + c;
        }
        __syncthreads();
        uint32_t off0 = val - eqc + sWs[4 + wv];     // exclusive prefix of eq-counts
        for (int s = 0; s < CH; ++s) {
            int e = t * CH + s;
            if (e < NA) {
                uint32_t k = sKeys[e];
                if (k == kth) {
                    if (off0 < rem)
                        sSel[cntgt + off0] = ((ull)k << 32) | (ull)(0xFFFFFFFFu - (uint32_t)e);
                    off0++;
                }
            }
        }
        __syncthreads();
    }

    // ---- rank sort: entries unique -> ranks are a permutation ----
    ull my0 = sSel[t];
    ull my1 = (t < KTOP - 256) ? sSel[256 + t] : 0ull;
    int r0 = 0, r1 = 0;
    for (int j = 0; j < KTOP; ++j) {
        ull v = sSel[j];                 // broadcast read
        r0 += (v > my0) ? 1 : 0;
        r1 += (v > my1) ? 1 : 0;
    }
    sSorted[r0] = my0;
    if (t < KTOP - 256) sSorted[r1] = my1;
    __syncthreads();

    // ---- keep-init ballots ----
    {
        bool f = ((uint32_t)(sSorted[t] >> 32)) > 0x007FFFFFu;
        ull m = __ballot(f);
        if (lane == 0) sKeepW[wv] = m;
        if (t < 64) {
            bool f2 = (t < KTOP - 256) && (((uint32_t)(sSorted[256 + t] >> 32)) > 0x007FFFFFu);
            ull m2 = __ballot(f2);
            if (t == 0) sKeepW[4] = m2;
        }
    }

    // ---- gather winners from pred: box + obj/conf/argmax; keep-independent outputs ----
    const size_t bo = (size_t)b * KTOP;
    for (int i = t; i < KTOP; i += 256) {
        ull s = sSorted[i];
        uint32_t a = 0xFFFFFFFFu - (uint32_t)(s & 0xFFFFFFFFull);
        const float* p = pred + ((size_t)b * NA + a) * 85;
        float x = p[0], y = p[1], w = p[2], h = p[3], obj = p[4];
        float best = p[5]; int bc = 0;
        for (int c = 1; c < NC; ++c) {       // sequential: argmax keeps FIRST max
            float v = p[5 + c];
            if (v > best) { best = v; bc = c; }
        }
        float hw = w * 0.5f, hh = h * 0.5f;
        float x1 = x - hw, y1 = y - hh, x2 = x + hw, y2 = y + hh;
        sBox[i] = make_float4(x1, y1, x2, y2);
        ((float4*)out)[bo + i] = make_float4(y1, x1, y2, x2);          // boxes_yxyx
        ((float2*)(out + O4))[bo + i] = make_float2((y1 + y2) * 0.5f,  // centers_yx
                                                    (x1 + x2) * 0.5f);
        out[O2 + bo + i] = fmaxf(obj, best);                           // scores
        out[O3 + bo + i] = (float)bc;                                  // classes
    }
    __syncthreads();

    // ---- IoU suppression masks in LDS ----
    for (int item = t; item < 5 * KTOP; item += 256) {
        int role = item / KTOP;          // lanes share role, consecutive i -> uniform j-loop
        int i = item - role * KTOP;
        float4 B = sBox[i];
        float x1 = B.x, y1 = B.y, x2 = B.z, y2 = B.w;
        float ai = fmaxf(x2 - x1, 0.0f) * fmaxf(y2 - y1, 0.0f);
        ull bits = 0ull;
        int j0 = role * 64;
        int jmax = j0 + 64; if (jmax > KTOP) jmax = KTOP;
        int jbeg = (j0 > i + 1) ? j0 : (i + 1);
        for (int j = jbeg; j < jmax; ++j) {
            float4 C = sBox[j];          // broadcast read
            float aj = fmaxf(C.z - C.x, 0.0f) * fmaxf(C.w - C.y, 0.0f);
            float iw = fminf(x2, C.z) - fmaxf(x1, C.x); iw = fmaxf(iw, 0.0f);
            float ih = fminf(y2, C.w) - fmaxf(y1, C.y); ih = fmaxf(ih, 0.0f);
            float inter = iw * ih;
            float den = ai + aj;         // mirror reference op order exactly
            den = den - inter;
            den = den + 1e-9f;
            float iou = inter / den;
            if (iou > 0.45f) bits |= (1ull << (j - j0));
        }
        sMask[item] = bits;
    }
    __syncthreads();

    // ---- greedy NMS on wave 0: masks in registers, ctz skip between accepted boxes ----
    if (t < 64) {
        ull rm[5][5];                    // rm[w][ww]: suppression row of box i=w*64+lane, word ww
        #pragma unroll
        for (int w = 0; w < 5; ++w) {
            int i = w * 64 + t;
            #pragma unroll
            for (int ww = 0; ww < 5; ++ww)
                rm[w][ww] = (i < KTOP) ? sMask[ww * KTOP + i] : 0ull;
        }
        ull kw[5];
        #pragma unroll
        for (int w = 0; w < 5; ++w) kw[w] = sKeepW[w];   // replicated in every lane
        #pragma unroll
        for (int w = 0; w < 5; ++w) {
            ull cur = kw[w];
            while (cur) {
                int ib = __builtin_ctzll(cur);           // accepted box i = w*64+ib
                ull m0 = __shfl(rm[w][0], ib);
                ull m1 = __shfl(rm[w][1], ib);
                ull m2 = __shfl(rm[w][2], ib);
                ull m3 = __shfl(rm[w][3], ib);
                ull m4 = __shfl(rm[w][4], ib);
                kw[0] &= ~m0; kw[1] &= ~m1; kw[2] &= ~m2; kw[3] &= ~m3; kw[4] &= ~m4;
                ull done = (ib == 63) ? 0ull : (~0ull << (ib + 1));
                cur = kw[w] & done;
            }
        }
        if (t == 0) {
            #pragma unroll
            for (int w = 0; w < 5; ++w) sKeepW[w] = kw[w];
        }
    }
    __syncthreads();

    // ---- keep + in_zone outputs ----
    for (int i = t; i < KTOP; i += 256) {
        int kp = (int)((sKeepW[i >> 6] >> (i & 63)) & 1ull);
        float4 B = sBox[i];
        float cy = (B.y + B.w) * 0.5f;   // same inputs & ops as centers output
        float cx = (B.x + B.z) * 0.5f;
        int cnt = 0;
        #pragma unroll
        for (int e = 0; e < 8; ++e) {
            float xi = sZone[2 * e], yi = sZone[2 * e + 1];
            int ep = (e + 7) & 7;        // zr = roll(zone, 1)
            float xj = sZone[2 * ep], yj = sZone[2 * ep + 1];
            bool gyi = yi > cy, gyj = yj > cy;
            if (gyi != gyj) {
                float gx = (xj - xi) * (cy - yi) / (yj - yi) + xi;
                if (gx > cx) cnt++;
            }
        }
        int inz = (((cnt & 1) != 0) && kp) ? 1 : 0;
        out[O1 + bo + i] = (float)inz;
        out[O5 + bo + i] = (float)kp;
    }
}

extern "C" void kernel_launch(void* const* d_in, const int* in_sizes, int n_in,
                              void* d_out, int out_size, void* d_ws, size_t ws_size,
                              hipStream_t stream) {
    const float* pred = (const float*)d_in[0];   // (32,8400,85) fp32
    const float* zone = (const float*)d_in[1];   // (8,2) fp32
    float* out = (float*)d_out;                  // 96000 fp32
    uint8_t* ws = (uint8_t*)d_ws;
    uint32_t* keys = (uint32_t*)ws;
    uint32_t* gHist = (uint32_t*)(ws + HIST_OFF);

    score_kernel<<<NB * NBLK, 128, 0, stream>>>(pred, keys, gHist);
    topk_nms_kernel<<<NB, 256, 0, stream>>>(pred, zone, keys, gHist, out);
}

// Round 8
// 205.516 us; speedup vs baseline: 1.6081x; 1.0555x over previous
//
#include <hip/hip_runtime.h>
#include <stdint.h>

typedef unsigned long long ull;

#define NA 8400
#define NB 32
#define KTOP 300
#define NC 80
#define CH 33            // 256*33 = 8448 >= 8400
#define NBLK 66          // score blocks per batch (66*128 = 8448 >= 8400)

// ws layout:
//   keys  uint32[32][8400]   @0          (1,075,200 B)
//   xywh4 float4[32][8400]   @XYWH_OFF   (4,300,800 B)
//   meta4 float4[32][8400]   @META_OFF   (4,300,800 B)
//   gHist uint32[32][256]    @HIST_OFF   (32,768 B, zeroed by hipMemsetAsync)
#define XYWH_OFF 1075200
#define META_OFF 5376000
#define HIST_OFF 9676800

// out layout: boxes_yxyx @0 ; in_zone @38400 ; scores @48000 ; classes @57600 ;
//             centers_yx @67200 ; keep @86400 ; total 96000 floats
#define O1 38400
#define O2 48000
#define O3 57600
#define O4 67200
#define O5 86400

// async global->LDS, 16B per lane; lds dest = wave-uniform base + lane*16
__device__ __forceinline__ void g2l16(const void* g, void* l) {
    __builtin_amdgcn_global_load_lds(
        (const __attribute__((address_space(1))) void*)g,
        (__attribute__((address_space(3))) void*)l, 16, 0, 0);
}

// ---------------- A: score key + packed details + per-batch histogram ----------------
__global__ __launch_bounds__(128) void score_kernel(const float* __restrict__ pred,
                                                    uint32_t* __restrict__ keys,
                                                    float4* __restrict__ xywh4,
                                                    float4* __restrict__ meta4,
                                                    uint32_t* __restrict__ gHist) {
    __shared__ float sP[128 * 85];
    __shared__ uint32_t sH[4 * 257];   // padded half-wave sub-hists (hot bins -> distinct banks)
    const int batch = blockIdx.x / NBLK;
    const int blk = blockIdx.x - batch * NBLK;
    const int t = threadIdx.x;
    const int lane = t & 63;
    const int wv = t >> 6;
    const int local0 = blk * 128;
    const int nval = (NA - local0 < 128) ? (NA - local0) : 128;   // tail block: 80

    for (int i = t; i < 4 * 257; i += 128) sH[i] = 0u;

    // async staging: contiguous lane order, wave-uniform LDS base
    const float4* g4 = (const float4*)(pred + ((size_t)batch * NA + local0) * 85);
    float4* l4 = (float4*)sP;
    const int n4 = nval * 85 / 4;      // 2720 (full) or 1700 (tail)
    for (int base = wv * 64; base < n4; base += 128) {
        int idx = base + lane;
        if (idx < n4) g2l16(g4 + idx, l4 + base);
    }
    __syncthreads();                   // drains vmcnt + lgkmcnt

    if (t < nval) {
        const float* p = sP + t * 85;
        float x = p[0], y = p[1], w = p[2], h = p[3], obj = p[4];
        // 4 interleaved first-max chains (strict > keeps lowest index within chain)
        float b0 = p[5], b1 = p[6], b2 = p[7], b3 = p[8];
        int i0 = 0, i1 = 1, i2 = 2, i3 = 3;
        #pragma unroll
        for (int c = 4; c < NC; c += 4) {
            float v0 = p[5 + c], v1 = p[6 + c], v2 = p[7 + c], v3 = p[8 + c];
            if (v0 > b0) { b0 = v0; i0 = c; }
            if (v1 > b1) { b1 = v1; i1 = c + 1; }
            if (v2 > b2) { b2 = v2; i2 = c + 2; }
            if (v3 > b3) { b3 = v3; i3 = c + 3; }
        }
        float best = fmaxf(fmaxf(b0, b1), fmaxf(b2, b3));
        int bi = 0x7FFFFFFF;           // overall first max = min index among equal chain winners
        if (b3 == best) bi = i3;
        if (b2 == best && i2 < bi) bi = i2;
        if (b1 == best && i1 < bi) bi = i1;
        if (b0 == best && i0 < bi) bi = i0;
        float sc = obj * best;
        uint32_t u = (sc >= 0.2f) ? (__float_as_uint(sc) | 0x80000000u) : 0x007FFFFFu;
        const size_t gi = (size_t)batch * NA + local0 + t;
        keys[gi] = u;
        xywh4[gi] = make_float4(x, y, w, h);
        meta4[gi] = make_float4(obj, best, (float)bi, 0.0f);
        atomicAdd(&sH[(t >> 5) * 257 + (u >> 24)], 1u);
    }
    __syncthreads();
    // merge sub-hists; one global atomic per nonzero bin (per-batch, pre-zeroed)
    uint32_t* gh = gHist + (size_t)batch * 256;
    for (int bin = t; bin < 256; bin += 128) {
        uint32_t v = sH[bin] + sH[257 + bin] + sH[514 + bin] + sH[771 + bin];
        if (v) atomicAdd(&gh[bin], v);
    }
}

// ---------------- B: fused top-300 select + gather + NMS + all outputs ----------------
__global__ __launch_bounds__(256) void topk_nms_kernel(const float4* __restrict__ xywh4,
                                                       const float4* __restrict__ meta4,
                                                       const float* __restrict__ zone,
                                                       const uint32_t* __restrict__ keys,
                                                       const uint32_t* __restrict__ gHist,
                                                       float* __restrict__ out) {
    #pragma clang fp contract(off)
    __shared__ uint32_t sKeys[8448];   // 33792 B
    __shared__ ull sSel[KTOP];
    __shared__ ull sSorted[KTOP];      // 4800 B
    __shared__ uint32_t sH4[4 * 257];  // 4112 B padded per-wave sub-hists (rounds 1-3)
    __shared__ float4 sBox[KTOP];      // 4800 B
    __shared__ ull sMask[5 * KTOP];    // 12000 B role-major: sMask[role*300 + i]
    __shared__ ull sKeepW[5];
    __shared__ float sZone[16];
    __shared__ uint32_t sWs[8];        // [0..3] wave sums, [4..7] exclusive wave offsets
    __shared__ uint32_t sBc[2];
    __shared__ int sCnt;

    const int b = blockIdx.x;
    const int t = threadIdx.x;
    const unsigned lane = t & 63;
    const int wv = t >> 6;
    const int sh = wv * 257;

    // async-load keys into LDS (2100 float4s), pad tail, load zone
    {
        const float4* k4 = (const float4*)(keys + (size_t)b * NA);
        float4* sk4 = (float4*)sKeys;
        for (int base = wv * 64; base < 2100; base += 256) {
            int idx = base + lane;
            if (idx < 2100) g2l16(k4 + idx, sk4 + base);
        }
    }
    if (t < 48) sKeys[NA + t] = 0u;
    if (t < 16) sZone[t] = zone[t];
    if (t == 0) sCnt = 0;
    __syncthreads();

    // ---- radix select: exact 300th-largest key; round 0 from per-batch histogram ----
    uint32_t prefix = 0, r = KTOP;
    for (int round = 0; round < 4; ++round) {
        const int shift = 24 - 8 * round;
        uint32_t h;
        if (round == 0) {
            h = gHist[(size_t)b * 256 + t];      // single coalesced load
        } else {
            for (int idx = t; idx < 4 * 257; idx += 256) sH4[idx] = 0u;
            __syncthreads();
            const uint32_t pmask = 0xFFFFFFFFu << (shift + 8);
            const uint32_t pval = prefix & pmask;
            for (int s = 0; s < CH; ++s) {
                int e = t * CH + s;
                if (e < NA) {
                    uint32_t k = sKeys[e];
                    if ((k & pmask) == pval)
                        atomicAdd(&sH4[sh + ((k >> shift) & 0xFFu)], 1u);
                }
            }
            __syncthreads();
            h = sH4[t] + sH4[257 + t] + sH4[514 + t] + sH4[771 + t];
        }
        // inclusive prefix scan over 256 bins: wave shfl scan + cross-wave combine
        uint32_t val = h;
        #pragma unroll
        for (int d = 1; d < 64; d <<= 1) {
            uint32_t v = __shfl_up(val, d);
            if (lane >= (unsigned)d) val += v;
        }
        if (lane == 63) sWs[wv] = val;
        __syncthreads();
        if (t == 0) {
            uint32_t a = sWs[0], b2 = sWs[1], c = sWs[2];
            sWs[4] = 0; sWs[5] = a; sWs[6] = a + b2; sWs[7] = a + b2 + c;
        }
        __syncthreads();
        uint32_t P = val + sWs[4 + wv];          // match-set keys with byte <= t
        uint32_t Total = sWs[7] + sWs[3];
        uint32_t above = Total - P;              // match-set keys with byte > t
        if (above < r && above + h >= r) {       // unique crossing bin
            sBc[0] = prefix | ((uint32_t)t << shift);
            sBc[1] = r - above;
        }
        __syncthreads();
        prefix = sBc[0]; r = sBc[1];
        __syncthreads();
    }
    const uint32_t kth = prefix;
    const uint32_t rem = r;
    const uint32_t cntgt = KTOP - rem;

    // ---- compact the top-300 set into sSel (unordered) ----
    {
        uint32_t eqc = 0;
        for (int s = 0; s < CH; ++s) {
            int e = t * CH + s;
            if (e < NA) {
                uint32_t k = sKeys[e];
                if (k > kth) {
                    int p = atomicAdd(&sCnt, 1);
                    sSel[p] = ((ull)k << 32) | (ull)(0xFFFFFFFFu - (uint32_t)e);
                } else if (k == kth) eqc++;
            }
        }
        uint32_t val = eqc;
        #pragma unroll
        for (int d = 1; d < 64; d <<= 1) {
            uint32_t v = __shfl_up(val, d);
            if (lane >= (unsigned)d) val += v;
        }
        if (lane == 63) sWs[wv] = val;
        __syncthreads();
        if (t == 0) {
            uint32_t a = sWs[0], b2 = sWs[1], c = sWs[2];
            sWs[4] = 0; sWs[5] = a; sWs[6] = a + b2; sWs[7] = a + b2 + c;
        }
        __syncthreads();
        uint32_t off0 = val - eqc + sWs[4 + wv];     // exclusive prefix of eq-counts
        for (int s = 0; s < CH; ++s) {
            int e = t * CH + s;
            if (e < NA) {
                uint32_t k = sKeys[e];
                if (k == kth) {
                    if (off0 < rem)
                        sSel[cntgt + off0] = ((ull)k << 32) | (ull)(0xFFFFFFFFu - (uint32_t)e);
                    off0++;
                }
            }
        }
        __syncthreads();
    }

    // ---- rank sort: entries unique -> ranks are a permutation ----
    ull my0 = sSel[t];
    ull my1 = (t < KTOP - 256) ? sSel[256 + t] : 0ull;
    int r0 = 0, r1 = 0;
    for (int j = 0; j < KTOP; ++j) {
        ull v = sSel[j];                 // broadcast read
        r0 += (v > my0) ? 1 : 0;
        r1 += (v > my1) ? 1 : 0;
    }
    sSorted[r0] = my0;
    if (t < KTOP - 256) sSorted[r1] = my1;
    __syncthreads();

    // ---- keep-init ballots ----
    {
        bool f = ((uint32_t)(sSorted[t] >> 32)) > 0x007FFFFFu;
        ull m = __ballot(f);
        if (lane == 0) sKeepW[wv] = m;
        if (t < 64) {
            bool f2 = (t < KTOP - 256) && (((uint32_t)(sSorted[256 + t] >> 32)) > 0x007FFFFFu);
            ull m2 = __ballot(f2);
            if (t == 0) sKeepW[4] = m2;
        }
    }

    // ---- gather packed winner details; keep-independent outputs ----
    const size_t bo = (size_t)b * KTOP;
    for (int i = t; i < KTOP; i += 256) {
        ull s = sSorted[i];
        uint32_t a = 0xFFFFFFFFu - (uint32_t)(s & 0xFFFFFFFFull);
        size_t g = (size_t)b * NA + a;
        float4 xw = xywh4[g];
        float4 mt = meta4[g];
        float hw = xw.z * 0.5f, hh = xw.w * 0.5f;
        float x1 = xw.x - hw, y1 = xw.y - hh, x2 = xw.x + hw, y2 = xw.y + hh;
        sBox[i] = make_float4(x1, y1, x2, y2);
        ((float4*)out)[bo + i] = make_float4(y1, x1, y2, x2);          // boxes_yxyx
        ((float2*)(out + O4))[bo + i] = make_float2((y1 + y2) * 0.5f,  // centers_yx
                                                    (x1 + x2) * 0.5f);
        out[O2 + bo + i] = fmaxf(mt.x, mt.y);                          // scores
        out[O3 + bo + i] = mt.z;                                       // classes
    }
    __syncthreads();

    // ---- IoU suppression masks in LDS ----
    for (int item = t; item < 5 * KTOP; item += 256) {
        int role = item / KTOP;          // lanes share role, consecutive i -> uniform j-loop
        int i = item - role * KTOP;
        float4 B = sBox[i];
        float x1 = B.x, y1 = B.y, x2 = B.z, y2 = B.w;
        float ai = fmaxf(x2 - x1, 0.0f) * fmaxf(y2 - y1, 0.0f);
        ull bits = 0ull;
        int j0 = role * 64;
        int jmax = j0 + 64; if (jmax > KTOP) jmax = KTOP;
        int jbeg = (j0 > i + 1) ? j0 : (i + 1);
        for (int j = jbeg; j < jmax; ++j) {
            float4 C = sBox[j];          // broadcast read
            float aj = fmaxf(C.z - C.x, 0.0f) * fmaxf(C.w - C.y, 0.0f);
            float iw = fminf(x2, C.z) - fmaxf(x1, C.x); iw = fmaxf(iw, 0.0f);
            float ih = fminf(y2, C.w) - fmaxf(y1, C.y); ih = fmaxf(ih, 0.0f);
            float inter = iw * ih;
            float den = ai + aj;         // mirror reference op order exactly
            den = den - inter;
            den = den + 1e-9f;
            float iou = inter / den;
            if (iou > 0.45f) bits |= (1ull << (j - j0));
        }
        sMask[item] = bits;
    }
    __syncthreads();

    // ---- greedy NMS on wave 0: masks in registers, ctz skip between accepted boxes ----
    if (t < 64) {
        ull rm[5][5];                    // rm[w][ww]: suppression row of box i=w*64+lane, word ww
        #pragma unroll
        for (int w = 0; w < 5; ++w) {
            int i = w * 64 + t;
            #pragma unroll
            for (int ww = 0; ww < 5; ++ww)
                rm[w][ww] = (i < KTOP) ? sMask[ww * KTOP + i] : 0ull;
        }
        ull kw[5];
        #pragma unroll
        for (int w = 0; w < 5; ++w) kw[w] = sKeepW[w];   // replicated in every lane
        #pragma unroll
        for (int w = 0; w < 5; ++w) {
            ull cur = kw[w];
            while (cur) {
                int ib = __builtin_ctzll(cur);           // accepted box i = w*64+ib
                ull m0 = __shfl(rm[w][0], ib);
                ull m1 = __shfl(rm[w][1], ib);
                ull m2 = __shfl(rm[w][2], ib);
                ull m3 = __shfl(rm[w][3], ib);
                ull m4 = __shfl(rm[w][4], ib);
                kw[0] &= ~m0; kw[1] &= ~m1; kw[2] &= ~m2; kw[3] &= ~m3; kw[4] &= ~m4;
                ull done = (ib == 63) ? 0ull : (~0ull << (ib + 1));
                cur = kw[w] & done;
            }
        }
        if (t == 0) {
            #pragma unroll
            for (int w = 0; w < 5; ++w) sKeepW[w] = kw[w];
        }
    }
    __syncthreads();

    // ---- keep + in_zone outputs ----
    for (int i = t; i < KTOP; i += 256) {
        int kp = (int)((sKeepW[i >> 6] >> (i & 63)) & 1ull);
        float4 B = sBox[i];
        float cy = (B.y + B.w) * 0.5f;   // same inputs & ops as centers output
        float cx = (B.x + B.z) * 0.5f;
        int cnt = 0;
        #pragma unroll
        for (int e = 0; e < 8; ++e) {
            float xi = sZone[2 * e], yi = sZone[2 * e + 1];
            int ep = (e + 7) & 7;        // zr = roll(zone, 1)
            float xj = sZone[2 * ep], yj = sZone[2 * ep + 1];
            bool gyi = yi > cy, gyj = yj > cy;
            if (gyi != gyj) {
                float gx = (xj - xi) * (cy - yi) / (yj - yi) + xi;
                if (gx > cx) cnt++;
            }
        }
        int inz = (((cnt & 1) != 0) && kp) ? 1 : 0;
        out[O1 + bo + i] = (float)inz;
        out[O5 + bo + i] = (float)kp;
    }
}

extern "C" void kernel_launch(void* const* d_in, const int* in_sizes, int n_in,
                              void* d_out, int out_size, void* d_ws, size_t ws_size,
                              hipStream_t stream) {
    const float* pred = (const float*)d_in[0];   // (32,8400,85) fp32
    const float* zone = (const float*)d_in[1];   // (8,2) fp32
    float* out = (float*)d_out;                  // 96000 fp32
    uint8_t* ws = (uint8_t*)d_ws;
    uint32_t* keys = (uint32_t*)ws;
    float4* xywh4 = (float4*)(ws + XYWH_OFF);
    float4* meta4 = (float4*)(ws + META_OFF);
    uint32_t* gHist = (uint32_t*)(ws + HIST_OFF);

    hipMemsetAsync(gHist, 0, NB * 256 * sizeof(uint32_t), stream);   // graph-capturable
    score_kernel<<<NB * NBLK, 128, 0, stream>>>(pred, keys, xywh4, meta4, gHist);
    topk_nms_kernel<<<NB, 256, 0, stream>>>(xywh4, meta4, zone, keys, gHist, out);
}